// Round 2
// baseline (479.777 us; speedup 1.0000x reference)
//
#include <hip/hip_runtime.h>

// Problem constants
static constexpr int NN = 10000;   // nodes
static constexpr int DD = 64;      // in/out dim
static constexpr int KP = 10240;   // padded K for M_T
static constexpr int BK = 128;     // K per inner iter
static constexpr int SPLITS = 8;   // K-split factor (grid.y)
static constexpr int KC = KP / SPLITS;  // 1280 K per block
static constexpr int ITERS = KC / BK;   // 10
static constexpr int BM = 64;      // rows per block

typedef __attribute__((ext_vector_type(4))) float f32x4;
typedef __attribute__((ext_vector_type(8))) short s16x8;

__device__ __forceinline__ unsigned short f2bf(float f) {
  // fp32 -> bf16 round-to-nearest-even (bit trick; inputs finite)
  unsigned u = __float_as_uint(f);
  return (unsigned short)((u + 0x7fffu + ((u >> 16) & 1u)) >> 16);
}

// ---------- prep: M_T[r][d][k] = bf16( sum_j H[k][j] * W_r[d][j] ), zero-padded to KP ----------
__global__ void prep_kernel(const float* __restrict__ H,
                            const float* __restrict__ W1,
                            const float* __restrict__ W2,
                            const float* __restrict__ W3,
                            unsigned short* __restrict__ mt) {
  const int r = blockIdx.y;
  const float* W = (r == 0) ? W1 : (r == 1) ? W2 : W3;
  const int wave = threadIdx.x >> 6;
  const int lane = threadIdx.x & 63;   // lane == output dim d
  f32x4 wr[16];
#pragma unroll
  for (int i = 0; i < 16; ++i) wr[i] = *(const f32x4*)&W[lane * 64 + i * 4];
  unsigned short* orow = mt + ((size_t)r * 64 + lane) * KP;
  const int kbase = blockIdx.x * 128 + wave * 32;
  for (int i = 0; i < 32; ++i) {
    const int k = kbase + i;
    if (k < NN) {
      float s = 0.f;
#pragma unroll
      for (int j = 0; j < 16; ++j) {
        f32x4 h = *(const f32x4*)&H[(size_t)k * 64 + j * 4]; // wave-uniform addr -> broadcast
        s += h[0] * wr[j][0] + h[1] * wr[j][1] + h[2] * wr[j][2] + h[3] * wr[j][3];
      }
      orow[k] = f2bf(s);
    } else {
      orow[k] = 0;  // zero pad k in [10000,10240)
    }
  }
}

// ---------- init: out[v][d] = bias[d] ----------
__global__ void init_out_kernel(const float* __restrict__ bias, float* __restrict__ out) {
  const int i = blockIdx.x * 256 + threadIdx.x;
  if (i < NN * DD) out[i] = bias[i & 63];
}

// ---------- main: out += A_r[:, kchunk] @ M_r[kchunk, :]  (bf16 MFMA) ----------
// No LDS, no barriers. B-fragments read directly from global (L1/L2-resident,
// all waves in a block hit identical addresses). K split 8 ways across grid.y;
// partial sums combined via atomicAdd (out pre-initialized to bias).
__global__ __launch_bounds__(256) void gcn_main(const float* __restrict__ A1,
                                                const float* __restrict__ A2,
                                                const float* __restrict__ A3,
                                                const unsigned short* __restrict__ mt,
                                                float* __restrict__ out) {
  const int r = blockIdx.z;
  const int s = blockIdx.y;
  const float* A = (r == 0) ? A1 : (r == 1) ? A2 : A3;
  const unsigned short* mtr = mt + (size_t)r * 64 * KP;

  const int wave = threadIdx.x >> 6;
  const int lane = threadIdx.x & 63;
  const int l15 = lane & 15;
  const int lhi = lane >> 4;
  const int v0 = blockIdx.x * BM;
  const int k0 = s * KC;

  // A row this lane streams (clamped for tail block; garbage rows never stored)
  int vA = v0 + wave * 16 + l15;
  if (vA > NN - 1) vA = NN - 1;
  const float* arow = A + (size_t)vA * NN;

  f32x4 acc[4] = {{0.f,0.f,0.f,0.f},{0.f,0.f,0.f,0.f},{0.f,0.f,0.f,0.f},{0.f,0.f,0.f,0.f}};
  f32x4 aF[4][2], aN[4][2];

  auto loadA = [&](f32x4 (&a)[4][2], int kb) {
    const bool guard = (kb + BK > NN);  // only final iters of last split
#pragma unroll
    for (int kk = 0; kk < 4; ++kk) {
      const int kf = kb + kk * 32 + lhi * 8;   // kf % 8 == 0, NN % 8 == 0
      if (!guard) {
        a[kk][0] = *(const f32x4*)(arow + kf);
        a[kk][1] = *(const f32x4*)(arow + kf + 4);
      } else {
        f32x4 z = {0.f, 0.f, 0.f, 0.f};
        if (kf < NN) {                          // kf<NN => kf+8<=NN (both mod 8)
          a[kk][0] = *(const f32x4*)(arow + kf);
          a[kk][1] = *(const f32x4*)(arow + kf + 4);
        } else {
          a[kk][0] = z; a[kk][1] = z;
        }
      }
    }
  };
  auto cvtA = [&](const f32x4& x, const f32x4& y) -> s16x8 {
    s16x8 v;
    v[0] = (short)f2bf(x[0]); v[1] = (short)f2bf(x[1]);
    v[2] = (short)f2bf(x[2]); v[3] = (short)f2bf(x[3]);
    v[4] = (short)f2bf(y[0]); v[5] = (short)f2bf(y[1]);
    v[6] = (short)f2bf(y[2]); v[7] = (short)f2bf(y[3]);
    return v;
  };

  // prologue: A frags for iter 0
  loadA(aF, k0);

#pragma unroll 2
  for (int t = 0; t < ITERS; ++t) {
    const int kb = k0 + t * BK;
    const bool pref = (t + 1 < ITERS);
    if (pref) loadA(aN, kb + BK);   // next A frags in flight (HBM latency hide)

    // B fragments direct from global (L1 broadcast across the block's waves):
    // b[kk][dt] = M_T[d = dt*16+l15][k = kb + (kk*4+lhi)*8 .. +8]
    s16x8 b[4][4];
#pragma unroll
    for (int kk = 0; kk < 4; ++kk)
#pragma unroll
      for (int dt = 0; dt < 4; ++dt)
        b[kk][dt] = *(const s16x8*)(mtr + (size_t)(dt * 16 + l15) * KP + kb + (kk * 4 + lhi) * 8);

#pragma unroll
    for (int kk = 0; kk < 4; ++kk) {
      s16x8 a = cvtA(aF[kk][0], aF[kk][1]);
#pragma unroll
      for (int dt = 0; dt < 4; ++dt)
        acc[dt] = __builtin_amdgcn_mfma_f32_16x16x32_bf16(a, b[kk][dt], acc[dt], 0, 0, 0);
    }
    if (pref) {
#pragma unroll
      for (int kk = 0; kk < 4; ++kk) { aF[kk][0] = aN[kk][0]; aF[kk][1] = aN[kk][1]; }
    }
  }

  // epilogue: C layout col=lane&15, row=(lane>>4)*4+i (m89-verified)
#pragma unroll
  for (int dt = 0; dt < 4; ++dt) {
    const int d = dt * 16 + l15;
#pragma unroll
    for (int i = 0; i < 4; ++i) {
      const int v = v0 + wave * 16 + lhi * 4 + i;
      if (v < NN) atomicAdd(&out[(size_t)v * DD + d], acc[dt][i]);
    }
  }
}

extern "C" void kernel_launch(void* const* d_in, const int* in_sizes, int n_in,
                              void* d_out, int out_size, void* d_ws, size_t ws_size,
                              hipStream_t stream) {
  const float* H    = (const float*)d_in[0];
  const float* A1   = (const float*)d_in[1];
  const float* A2   = (const float*)d_in[2];
  const float* A3   = (const float*)d_in[3];
  const float* W1   = (const float*)d_in[4];
  const float* W2   = (const float*)d_in[5];
  const float* W3   = (const float*)d_in[6];
  const float* bias = (const float*)d_in[7];
  float* out = (float*)d_out;
  unsigned short* mt = (unsigned short*)d_ws;  // M_T[3][64][KP] bf16 = 3.75 MB

  prep_kernel<<<dim3(KP / 128, 3), 256, 0, stream>>>(H, W1, W2, W3, mt);
  init_out_kernel<<<dim3((NN * DD + 255) / 256), 256, 0, stream>>>(bias, out);
  gcn_main<<<dim3((NN + BM - 1) / BM, SPLITS, 3), 256, 0, stream>>>(A1, A2, A3, mt, out);
}

// Round 3
// 317.479 us; speedup vs baseline: 1.5112x; 1.5112x over previous
//
#include <hip/hip_runtime.h>

// Problem constants
static constexpr int NN = 10000;   // nodes
static constexpr int DD = 64;      // in/out dim
static constexpr int KP = 10240;   // padded K for M_T
static constexpr int BK = 128;     // K per inner iter
static constexpr int SPLITS = 4;   // K-split factor (grid.y)
static constexpr int KC = KP / SPLITS;  // 2560 K per block
static constexpr int ITERS = KC / BK;   // 20
static constexpr int BM = 64;      // rows per block

typedef __attribute__((ext_vector_type(4))) float f32x4;
typedef __attribute__((ext_vector_type(8))) short s16x8;

__device__ __forceinline__ unsigned short f2bf(float f) {
  // fp32 -> bf16 round-to-nearest-even (bit trick; inputs finite)
  unsigned u = __float_as_uint(f);
  return (unsigned short)((u + 0x7fffu + ((u >> 16) & 1u)) >> 16);
}

// ---------- prep: M_T[r][d][k] = bf16( sum_j H[k][j] * W_r[d][j] ), zero-padded to KP ----------
__global__ void prep_kernel(const float* __restrict__ H,
                            const float* __restrict__ W1,
                            const float* __restrict__ W2,
                            const float* __restrict__ W3,
                            unsigned short* __restrict__ mt) {
  const int r = blockIdx.y;
  const float* W = (r == 0) ? W1 : (r == 1) ? W2 : W3;
  const int wave = threadIdx.x >> 6;
  const int lane = threadIdx.x & 63;   // lane == output dim d
  f32x4 wr[16];
#pragma unroll
  for (int i = 0; i < 16; ++i) wr[i] = *(const f32x4*)&W[lane * 64 + i * 4];
  unsigned short* orow = mt + ((size_t)r * 64 + lane) * KP;
  const int kbase = blockIdx.x * 128 + wave * 32;
  for (int i = 0; i < 32; ++i) {
    const int k = kbase + i;
    if (k < NN) {
      float s = 0.f;
#pragma unroll
      for (int j = 0; j < 16; ++j) {
        f32x4 h = *(const f32x4*)&H[(size_t)k * 64 + j * 4]; // wave-uniform addr -> broadcast
        s += h[0] * wr[j][0] + h[1] * wr[j][1] + h[2] * wr[j][2] + h[3] * wr[j][3];
      }
      orow[k] = f2bf(s);
    } else {
      orow[k] = 0;  // zero pad k in [10000,10240)
    }
  }
}

// ---------- init: out[v][d] = bias[d] ----------
__global__ void init_out_kernel(const float* __restrict__ bias, float* __restrict__ out) {
  const int i = blockIdx.x * 256 + threadIdx.x;
  if (i < NN * DD) out[i] = bias[i & 63];
}

// ---------- main: out += A_r[:, kchunk] @ M_r[kchunk, :]  (bf16 MFMA) ----------
// B staged in LDS (double-buffered, XOR-swizzled granules -> conflict-free),
// A double-buffered in regs. K split 4 ways (grid.y); partials via atomicAdd.
__global__ __launch_bounds__(256) void gcn_main(const float* __restrict__ A1,
                                                const float* __restrict__ A2,
                                                const float* __restrict__ A3,
                                                const unsigned short* __restrict__ mt,
                                                float* __restrict__ out) {
  // [buf][row][granule*8] halfwords; row = 128 hw = 256 B = 16 granules of 16 B.
  // Granule swizzle g' = g ^ (row&7) on BOTH write and read (reg-staged).
  __shared__ __align__(16) unsigned short mlds[2][64][128];

  const int r = blockIdx.z;
  const int s = blockIdx.y;
  const float* A = (r == 0) ? A1 : (r == 1) ? A2 : A3;
  const unsigned short* mtr = mt + (size_t)r * 64 * KP;

  const int wave = threadIdx.x >> 6;
  const int lane = threadIdx.x & 63;
  const int l15 = lane & 15;
  const int lhi = lane >> 4;
  const int v0 = blockIdx.x * BM;
  const int k0 = s * KC;

  // A row this lane streams (clamped for tail block; garbage rows never stored)
  int vA = v0 + wave * 16 + l15;
  if (vA > NN - 1) vA = NN - 1;
  const float* arow = A + (size_t)vA * NN;

  // M staging: wave stages rows [16w,16w+16); lane -> (row srow, 64B segment sseg)
  const int srow = wave * 16 + l15;
  const int sseg = lhi;
  const unsigned short* mrow = mtr + (size_t)srow * KP + k0 + sseg * 32;

  f32x4 acc[4] = {{0.f,0.f,0.f,0.f},{0.f,0.f,0.f,0.f},{0.f,0.f,0.f,0.f},{0.f,0.f,0.f,0.f}};
  f32x4 aF[4][2], aN[4][2];
  s16x8 mS[4];

  auto loadM = [&](int t) {
#pragma unroll
    for (int j = 0; j < 4; ++j) mS[j] = *(const s16x8*)(mrow + (size_t)t * BK + j * 8);
  };
  auto writeM = [&](int buf) {
#pragma unroll
    for (int j = 0; j < 4; ++j) {
      const int g = sseg * 4 + j;
      const int gs = g ^ (srow & 7);           // XOR swizzle
      *(s16x8*)&mlds[buf][srow][gs * 8] = mS[j];
    }
  };
  auto loadA = [&](f32x4 (&a)[4][2], int kb) {
    const bool guard = (kb + BK > NN);  // only final iters of last split
#pragma unroll
    for (int kk = 0; kk < 4; ++kk) {
      const int kf = kb + kk * 32 + lhi * 8;   // kf % 8 == 0, NN % 8 == 0
      if (!guard) {
        a[kk][0] = *(const f32x4*)(arow + kf);
        a[kk][1] = *(const f32x4*)(arow + kf + 4);
      } else {
        f32x4 z = {0.f, 0.f, 0.f, 0.f};
        if (kf < NN) {                          // kf<NN => kf+8<=NN (both mod 8)
          a[kk][0] = *(const f32x4*)(arow + kf);
          a[kk][1] = *(const f32x4*)(arow + kf + 4);
        } else {
          a[kk][0] = z; a[kk][1] = z;
        }
      }
    }
  };
  auto cvtA = [&](const f32x4& x, const f32x4& y) -> s16x8 {
    s16x8 v;
    v[0] = (short)f2bf(x[0]); v[1] = (short)f2bf(x[1]);
    v[2] = (short)f2bf(x[2]); v[3] = (short)f2bf(x[3]);
    v[4] = (short)f2bf(y[0]); v[5] = (short)f2bf(y[1]);
    v[6] = (short)f2bf(y[2]); v[7] = (short)f2bf(y[3]);
    return v;
  };

  // prologue: stage iter 0
  loadM(0);
  loadA(aF, k0);
  writeM(0);
  __syncthreads();

  for (int t = 0; t < ITERS; ++t) {
    const int buf = t & 1;
    const bool pref = (t + 1 < ITERS);
    if (pref) {
      loadM(t + 1);              // global -> regs (L2/L3-resident M)
      loadA(aN, k0 + (t + 1) * BK);  // prefetch next A frags (HBM latency hide)
    }
#pragma unroll
    for (int kk = 0; kk < 4; ++kk) {
      s16x8 a = cvtA(aF[kk][0], aF[kk][1]);
#pragma unroll
      for (int dt = 0; dt < 4; ++dt) {
        const int rrow = dt * 16 + l15;
        const int g = kk * 4 + lhi;
        s16x8 b = *(const s16x8*)&mlds[buf][rrow][(g ^ (rrow & 7)) * 8];
        acc[dt] = __builtin_amdgcn_mfma_f32_16x16x32_bf16(a, b, acc[dt], 0, 0, 0);
      }
    }
    if (pref) writeM(buf ^ 1);
    __syncthreads();
    if (pref) {
#pragma unroll
      for (int kk = 0; kk < 4; ++kk) { aF[kk][0] = aN[kk][0]; aF[kk][1] = aN[kk][1]; }
    }
  }

  // epilogue: C layout col=lane&15, row=(lane>>4)*4+i (m89-verified)
#pragma unroll
  for (int dt = 0; dt < 4; ++dt) {
    const int d = dt * 16 + l15;
#pragma unroll
    for (int i = 0; i < 4; ++i) {
      const int v = v0 + wave * 16 + lhi * 4 + i;
      if (v < NN) atomicAdd(&out[(size_t)v * DD + d], acc[dt][i]);
    }
  }
}

extern "C" void kernel_launch(void* const* d_in, const int* in_sizes, int n_in,
                              void* d_out, int out_size, void* d_ws, size_t ws_size,
                              hipStream_t stream) {
  const float* H    = (const float*)d_in[0];
  const float* A1   = (const float*)d_in[1];
  const float* A2   = (const float*)d_in[2];
  const float* A3   = (const float*)d_in[3];
  const float* W1   = (const float*)d_in[4];
  const float* W2   = (const float*)d_in[5];
  const float* W3   = (const float*)d_in[6];
  const float* bias = (const float*)d_in[7];
  float* out = (float*)d_out;
  unsigned short* mt = (unsigned short*)d_ws;  // M_T[3][64][KP] bf16 = 3.75 MB

  prep_kernel<<<dim3(KP / 128, 3), 256, 0, stream>>>(H, W1, W2, W3, mt);
  init_out_kernel<<<dim3((NN * DD + 255) / 256), 256, 0, stream>>>(bias, out);
  gcn_main<<<dim3((NN + BM - 1) / BM, SPLITS, 3), 256, 0, stream>>>(A1, A2, A3, mt, out);
}